// Round 9
// baseline (180.396 us; speedup 1.0000x reference)
//
#include <hip/hip_runtime.h>
#include <cstdint>

#define NEG 0.2f
#define BSH 4
#define BNODES 16
#define CAP 768
#define EPT 3
#define SBSH 9
#define SBN 512
#define CCAP 18000
#define CCHUNK 3328
#define CEPT 13
#define LOG2E 1.44269504088896f

typedef __attribute__((ext_vector_type(8))) short short8v;
typedef __attribute__((ext_vector_type(4))) float f32x4;

__device__ __forceinline__ unsigned short f2bf(float f) {
  unsigned u = __float_as_uint(f);
  return (unsigned short)((u + 0x7FFFu + ((u >> 16) & 1u)) >> 16);
}

// ---- prep: W transpose->bf16, qe[h] = 0.6*log2e*(att_h . We_h) --------------------
__global__ __launch_bounds__(256) void k_prep(const float* __restrict__ Wl,
    const float* __restrict__ Wr, const float* __restrict__ We,
    const float* __restrict__ att, unsigned short* __restrict__ WtB,
    float* __restrict__ qe) {
  int mat = blockIdx.x;
  const float* W = mat ? Wr : Wl;
  for (int i = threadIdx.x; i < 16384; i += 256) {
    int c = i >> 7, k = i & 127;
    WtB[mat * 16384 + c * 128 + k] = f2bf(W[k * 128 + c]);
  }
  if (mat == 0) {
    __shared__ float tmp[128];
    if (threadIdx.x < 128) tmp[threadIdx.x] = att[threadIdx.x] * We[threadIdx.x];
    __syncthreads();
    if (threadIdx.x < 4) {
      float s = 0.f;
      for (int c = 0; c < 32; ++c) s += tmp[threadIdx.x * 32 + c];
      qe[threadIdx.x] = 0.6f * LOG2E * s;
    }
  }
}

// ---- MFMA GEMM: xl=x@Wl+bl, xr=x@Wr+br (bf16 out) + ql/qr head-dots --------------
__global__ __launch_bounds__(256) void k_gemm(const float* __restrict__ x,
    const unsigned short* __restrict__ WtB, const float* __restrict__ att,
    const float* __restrict__ bl, const float* __restrict__ br,
    unsigned short* __restrict__ xlb, unsigned short* __restrict__ xrb,
    float* __restrict__ ql, float* __restrict__ qr, int n) {
  __shared__ __align__(16) unsigned short xs[64][136];
  __shared__ __align__(16) unsigned short Wt[128][136];
  int tid = threadIdx.x;
  int B0 = blockIdx.x * 64;
  for (int i = tid; i < 64 * 32; i += 256) {
    int r = i >> 5, c4 = (i & 31) * 4;
    ushort4 o = {0, 0, 0, 0};
    if (B0 + r < n) {
      float4 v = *(const float4*)(x + (size_t)(B0 + r) * 128 + c4);
      o = make_ushort4(f2bf(v.x), f2bf(v.y), f2bf(v.z), f2bf(v.w));
    }
    *(ushort4*)&xs[r][c4] = o;
  }
  int wv = tid >> 6, lane = tid & 63;
  int l15 = lane & 15, g = lane >> 4;
  int R0 = wv * 16;
  float attv[8];
  #pragma unroll
  for (int t = 0; t < 8; ++t) attv[t] = 0.6f * LOG2E * att[t * 16 + l15];
  for (int mat = 0; mat < 2; ++mat) {
    __syncthreads();
    for (int i = tid; i < 128 * 32; i += 256) {
      int c = i >> 5, k4 = (i & 31) * 4;
      *(ushort4*)&Wt[c][k4] = *(const ushort4*)(WtB + (size_t)mat * 16384 + c * 128 + k4);
    }
    __syncthreads();
    f32x4 acc[8];
    #pragma unroll
    for (int t = 0; t < 8; ++t) acc[t] = {0.f, 0.f, 0.f, 0.f};
    #pragma unroll
    for (int kc = 0; kc < 4; ++kc) {
      int k0 = kc * 32 + g * 8;
      short8v a = *(const short8v*)&xs[R0 + l15][k0];
      #pragma unroll
      for (int t = 0; t < 8; ++t) {
        short8v b = *(const short8v*)&Wt[t * 16 + l15][k0];
        acc[t] = __builtin_amdgcn_mfma_f32_16x16x32_bf16(a, b, acc[t], 0, 0, 0);
      }
    }
    const float* bias = mat ? br : bl;
    unsigned short* yp = mat ? xrb : xlb;
    float* qdst = mat ? qr : ql;
    float qp0[4] = {0, 0, 0, 0}, qp1[4] = {0, 0, 0, 0};
    float qp2[4] = {0, 0, 0, 0}, qp3[4] = {0, 0, 0, 0};
    #pragma unroll
    for (int t = 0; t < 8; ++t) {
      int col = t * 16 + l15;
      float bv = bias[col];
      float av = attv[t];
      #pragma unroll
      for (int q = 0; q < 4; ++q) {
        int row = B0 + R0 + g * 4 + q;
        unsigned short hb = f2bf(acc[t][q] + bv);
        if (row < n) yp[(size_t)row * 128 + col] = hb;
        float fr = __uint_as_float(((unsigned)hb) << 16);
        float c = av * fr;
        if (q == 0) qp0[t >> 1] += c;
        else if (q == 1) qp1[t >> 1] += c;
        else if (q == 2) qp2[t >> 1] += c;
        else qp3[t >> 1] += c;
      }
    }
    #pragma unroll
    for (int m2 = 1; m2 < 16; m2 <<= 1) {
      #pragma unroll
      for (int h2 = 0; h2 < 4; ++h2) {
        qp0[h2] += __shfl_xor(qp0[h2], m2);
        qp1[h2] += __shfl_xor(qp1[h2], m2);
        qp2[h2] += __shfl_xor(qp2[h2], m2);
        qp3[h2] += __shfl_xor(qp3[h2], m2);
      }
    }
    if (l15 < 4) {
      float v0 = (l15 == 0) ? qp0[0] : (l15 == 1) ? qp0[1] : (l15 == 2) ? qp0[2] : qp0[3];
      float v1 = (l15 == 0) ? qp1[0] : (l15 == 1) ? qp1[1] : (l15 == 2) ? qp1[2] : qp1[3];
      float v2 = (l15 == 0) ? qp2[0] : (l15 == 1) ? qp2[1] : (l15 == 2) ? qp2[2] : qp2[3];
      float v3 = (l15 == 0) ? qp3[0] : (l15 == 1) ? qp3[1] : (l15 == 2) ? qp3[2] : qp3[3];
      int rb = B0 + R0 + g * 4;
      if (rb + 0 < n) qdst[(rb + 0) * 4 + l15] = v0;
      if (rb + 1 < n) qdst[(rb + 1) * 4 + l15] = v1;
      if (rb + 2 < n) qdst[(rb + 2) * 4 + l15] = v2;
      if (rb + 3 < n) qdst[(rb + 3) * 4 + l15] = v3;
    }
  }
}

// ---- phase A: coarse scatter into superbucket slabs ------------------------------
__global__ __launch_bounds__(256) void k_coarse(const int* __restrict__ eidx,
    const float* __restrict__ ew, unsigned* __restrict__ gsb,
    int2* __restrict__ csb, int E, int NSB) {
  __shared__ unsigned cnt[128];
  __shared__ unsigned base[128];
  int c0 = blockIdx.x * CCHUNK;
  int c1 = min(E, c0 + CCHUNK);
  if (c0 >= c1) return;
  for (int b = threadIdx.x; b < NSB; b += 256) cnt[b] = 0u;
  __syncthreads();
  unsigned dreg[CEPT];
  #pragma unroll
  for (int k = 0; k < CEPT; ++k) {
    int i = c0 + threadIdx.x + k * 256;
    unsigned d = 0u;
    if (i < c1) {
      d = (unsigned)eidx[E + i];
      atomicAdd(&cnt[d >> SBSH], 1u);
    }
    dreg[k] = d;
  }
  __syncthreads();
  for (int b = threadIdx.x; b < NSB; b += 256) {
    unsigned c = cnt[b];
    base[b] = c ? atomicAdd(&gsb[b], c) : 0u;
    cnt[b] = 0u;
  }
  __syncthreads();
  #pragma unroll
  for (int k = 0; k < CEPT; ++k) {
    int i = c0 + threadIdx.x + k * 256;
    if (i < c1) {
      unsigned d = dreg[k];
      unsigned b = d >> SBSH;
      unsigned slot = base[b] + atomicAdd(&cnt[b], 1u);
      if (slot < CCAP)
        csb[(size_t)b * CCAP + slot] =
            make_int2((eidx[i] << SBSH) | (int)(d & (SBN - 1)), __float_as_int(ew[i]));
    }
  }
}

// ---- phase B: split superbucket into 32 fine-bucket slabs (single pass) ----------
__global__ __launch_bounds__(1024) void k_fine(const unsigned* __restrict__ gsb,
    const int2* __restrict__ csb, int2* __restrict__ ebkt,
    unsigned* __restrict__ fcnt, int NB) {
  __shared__ unsigned cnt[32];
  int sb = blockIdx.x;
  int ne = min((int)gsb[sb], CCAP);
  const int2* src = csb + (size_t)sb * CCAP;
  if (threadIdx.x < 32) cnt[threadIdx.x] = 0u;
  __syncthreads();
  for (int i = threadIdx.x; i < ne; i += 1024) {
    int2 e = src[i];
    int fb = (e.x >> 4) & 31;
    unsigned slot = atomicAdd(&cnt[fb], 1u);
    if (slot < CAP) {
      int packed = ((e.x >> SBSH) << 4) | (e.x & 15);
      ebkt[(size_t)(sb * 32 + fb) * CAP + slot] = make_int2(packed, e.y);
    }
  }
  __syncthreads();
  if (threadIdx.x < 32) {
    int fb = sb * 32 + (int)threadIdx.x;
    if (fb < NB) fcnt[fb] = min(cnt[threadIdx.x], (unsigned)CAP);
  }
}

// ---- fused: LDS counting-sort + softmax agg (8 lanes/edge, abs-decomposed score) --
__global__ __launch_bounds__(256) void k_agg(
    const unsigned* __restrict__ fcnt, const int2* __restrict__ ebkt,
    const unsigned short* __restrict__ xlb, const unsigned short* __restrict__ xrb,
    const float* __restrict__ ql, const float* __restrict__ qr,
    const float* __restrict__ qe, const float* __restrict__ We,
    const float* __restrict__ att, const float* __restrict__ bias,
    float* __restrict__ out, int n) {
  __shared__ int2 es[CAP];
  __shared__ unsigned rp[BNODES + 1];
  __shared__ unsigned cur[BNODES];
  __shared__ unsigned scnt[BNODES];
  int tid = threadIdx.x;
  int lane = tid & 63, wv = tid >> 6;
  int bkt = blockIdx.x;
  int ne = min((int)fcnt[bkt], CAP);
  const int2* srcp = ebkt + (size_t)bkt * CAP;
  if (tid < BNODES) scnt[tid] = 0u;
  __syncthreads();
  int2 er[EPT];
  #pragma unroll
  for (int k = 0; k < EPT; ++k) {
    int i = tid + k * 256;
    if (i < ne) {
      er[k] = srcp[i];
      atomicAdd(&scnt[er[k].x & (BNODES - 1)], 1u);
    }
  }
  __syncthreads();
  if (tid < 64) {
    unsigned s = (lane < BNODES) ? scnt[lane] : 0u;
    #pragma unroll
    for (int off = 1; off < BNODES; off <<= 1) {
      unsigned t = __shfl_up(s, off);
      if (lane >= off) s += t;
    }
    if (lane < BNODES) { rp[lane + 1] = s; cur[lane] = 0u; }
    if (lane == 0) rp[0] = 0u;
  }
  __syncthreads();
  #pragma unroll
  for (int k = 0; k < EPT; ++k) {
    int i = tid + k * 256;
    if (i < ne) {
      int dl = er[k].x & (BNODES - 1);
      unsigned slot = rp[dl] + atomicAdd(&cur[dl], 1u);
      es[slot] = make_int2(er[k].x >> BSH, er[k].y);
    }
  }
  __syncthreads();

  int l8 = lane & 7, g3 = lane >> 3;    // 8 lanes/edge, 8 edges/iter
  int ch0 = l8 * 16;                    // 16 channels per lane
  int h = l8 >> 1;
  float wec[16], atc[16];
  #pragma unroll
  for (int k = 0; k < 4; ++k) {
    float4 w4 = *(const float4*)(We + ch0 + k * 4);
    wec[k * 4 + 0] = w4.x; wec[k * 4 + 1] = w4.y;
    wec[k * 4 + 2] = w4.z; wec[k * 4 + 3] = w4.w;
    float4 a4 = *(const float4*)(att + ch0 + k * 4);
    atc[k * 4 + 0] = 0.4f * LOG2E * a4.x; atc[k * 4 + 1] = 0.4f * LOG2E * a4.y;
    atc[k * 4 + 2] = 0.4f * LOG2E * a4.z; atc[k * 4 + 3] = 0.4f * LOG2E * a4.w;
  }
  float qeh = qe[h];

  for (int dl = wv; dl < BNODES; dl += 4) {
    int d = (bkt << BSH) + dl;
    if (d >= n) break;
    int s0 = (int)rp[dl], s1 = (int)rp[dl + 1];
    float xrv[16];
    {
      uint4 a = *(const uint4*)(xrb + ((size_t)d << 7) + ch0);
      uint4 b = *(const uint4*)(xrb + ((size_t)d << 7) + ch0 + 8);
      xrv[0] = __uint_as_float(a.x << 16);  xrv[1] = __uint_as_float(a.x & 0xFFFF0000u);
      xrv[2] = __uint_as_float(a.y << 16);  xrv[3] = __uint_as_float(a.y & 0xFFFF0000u);
      xrv[4] = __uint_as_float(a.z << 16);  xrv[5] = __uint_as_float(a.z & 0xFFFF0000u);
      xrv[6] = __uint_as_float(a.w << 16);  xrv[7] = __uint_as_float(a.w & 0xFFFF0000u);
      xrv[8] = __uint_as_float(b.x << 16);  xrv[9] = __uint_as_float(b.x & 0xFFFF0000u);
      xrv[10] = __uint_as_float(b.y << 16); xrv[11] = __uint_as_float(b.y & 0xFFFF0000u);
      xrv[12] = __uint_as_float(b.z << 16); xrv[13] = __uint_as_float(b.z & 0xFFFF0000u);
      xrv[14] = __uint_as_float(b.w << 16); xrv[15] = __uint_as_float(b.w & 0xFFFF0000u);
    }
    float qrd = qr[d * 4 + h];
    float acc[16];
    #pragma unroll
    for (int k = 0; k < 16; ++k) acc[k] = 0.f;
    float den = 0.f, wmax = -INFINITY;
    int idx = s0 + g3;
    bool valid = idx < s1;
    int2 ev = make_int2(0, 0);
    uint4 xqa = {0, 0, 0, 0}, xqb = {0, 0, 0, 0};
    float qls = 0.f;
    if (valid) {
      ev = es[idx];
      xqa = *(const uint4*)(xlb + ((size_t)ev.x << 7) + ch0);
      xqb = *(const uint4*)(xlb + ((size_t)ev.x << 7) + ch0 + 8);
      qls = ql[ev.x * 4 + h];
    }
    for (int j = s0; j < s1; j += 8) {
      int idxn = j + 8 + g3;
      bool vn = idxn < s1;
      int2 evn = ev; uint4 xan = xqa, xbn = xqb; float qln = qls;
      if (vn) {
        evn = es[idxn];
        xan = *(const uint4*)(xlb + ((size_t)evn.x << 7) + ch0);
        xbn = *(const uint4*)(xlb + ((size_t)evn.x << 7) + ch0 + 8);
        qln = ql[evn.x * 4 + h];
      }
      if (valid) {
        float w = __int_as_float(ev.y);
        wmax = fmaxf(wmax, w);
        float lin = qls + fmaf(w, qeh, qrd);
        float xv[16];
        xv[0] = __uint_as_float(xqa.x << 16);  xv[1] = __uint_as_float(xqa.x & 0xFFFF0000u);
        xv[2] = __uint_as_float(xqa.y << 16);  xv[3] = __uint_as_float(xqa.y & 0xFFFF0000u);
        xv[4] = __uint_as_float(xqa.z << 16);  xv[5] = __uint_as_float(xqa.z & 0xFFFF0000u);
        xv[6] = __uint_as_float(xqa.w << 16);  xv[7] = __uint_as_float(xqa.w & 0xFFFF0000u);
        xv[8] = __uint_as_float(xqb.x << 16);  xv[9] = __uint_as_float(xqb.x & 0xFFFF0000u);
        xv[10] = __uint_as_float(xqb.y << 16); xv[11] = __uint_as_float(xqb.y & 0xFFFF0000u);
        xv[12] = __uint_as_float(xqb.z << 16); xv[13] = __uint_as_float(xqb.z & 0xFFFF0000u);
        xv[14] = __uint_as_float(xqb.w << 16); xv[15] = __uint_as_float(xqb.w & 0xFFFF0000u);
        float nl = 0.f;
        #pragma unroll
        for (int k = 0; k < 16; ++k) {
          float t = xv[k] + fmaf(w, wec[k], xrv[k]);
          nl = fmaf(atc[k], fabsf(t), nl);
        }
        nl += __shfl_xor(nl, 1);
        float pe = exp2f(lin + nl);
        den += pe;
        #pragma unroll
        for (int k = 0; k < 16; ++k) acc[k] = fmaf(pe, xv[k], acc[k]);
      }
      ev = evn; xqa = xan; xqb = xbn; qls = qln; valid = vn;
    }
    // merge the 8 edge-groups
    #pragma unroll
    for (int mask = 8; mask <= 32; mask <<= 1) {
      den += __shfl_xor(den, mask);
      #pragma unroll
      for (int k = 0; k < 16; ++k) acc[k] += __shfl_xor(acc[k], mask);
      wmax = fmaxf(wmax, __shfl_xor(wmax, mask));
    }
    // self-loop with weight = max incoming (0 if none)
    {
      float wl = (wmax > -INFINITY) ? wmax : 0.f;
      uint4 a = *(const uint4*)(xlb + ((size_t)d << 7) + ch0);
      uint4 b = *(const uint4*)(xlb + ((size_t)d << 7) + ch0 + 8);
      float xv[16];
      xv[0] = __uint_as_float(a.x << 16);  xv[1] = __uint_as_float(a.x & 0xFFFF0000u);
      xv[2] = __uint_as_float(a.y << 16);  xv[3] = __uint_as_float(a.y & 0xFFFF0000u);
      xv[4] = __uint_as_float(a.z << 16);  xv[5] = __uint_as_float(a.z & 0xFFFF0000u);
      xv[6] = __uint_as_float(a.w << 16);  xv[7] = __uint_as_float(a.w & 0xFFFF0000u);
      xv[8] = __uint_as_float(b.x << 16);  xv[9] = __uint_as_float(b.x & 0xFFFF0000u);
      xv[10] = __uint_as_float(b.y << 16); xv[11] = __uint_as_float(b.y & 0xFFFF0000u);
      xv[12] = __uint_as_float(b.z << 16); xv[13] = __uint_as_float(b.z & 0xFFFF0000u);
      xv[14] = __uint_as_float(b.w << 16); xv[15] = __uint_as_float(b.w & 0xFFFF0000u);
      float lin = ql[d * 4 + h] + fmaf(wl, qeh, qrd);
      float nl = 0.f;
      #pragma unroll
      for (int k = 0; k < 16; ++k) {
        float t = xv[k] + fmaf(wl, wec[k], xrv[k]);
        nl = fmaf(atc[k], fabsf(t), nl);
      }
      nl += __shfl_xor(nl, 1);
      float pe = exp2f(lin + nl);
      den += pe;
      #pragma unroll
      for (int k = 0; k < 16; ++k) acc[k] = fmaf(pe, xv[k], acc[k]);
    }
    if (g3 == 0) {
      float r = 1.0f / den;
      float* op = out + (size_t)d * 128 + ch0;
      #pragma unroll
      for (int k4 = 0; k4 < 4; ++k4) {
        float4 bv = *(const float4*)(bias + ch0 + k4 * 4);
        float4 o;
        o.x = acc[k4 * 4 + 0] * r + bv.x;
        o.y = acc[k4 * 4 + 1] * r + bv.y;
        o.z = acc[k4 * 4 + 2] * r + bv.z;
        o.w = acc[k4 * 4 + 3] * r + bv.w;
        *(float4*)(op + k4 * 4) = o;
      }
    }
  }
}

extern "C" void kernel_launch(void* const* d_in, const int* in_sizes, int n_in,
                              void* d_out, int out_size, void* d_ws, size_t ws_size,
                              hipStream_t stream) {
  const float* x     = (const float*)d_in[0];
  const int*   eidx  = (const int*)d_in[1];
  const float* ew_in = (const float*)d_in[2];
  const float* Wl    = (const float*)d_in[3];
  const float* bl    = (const float*)d_in[4];
  const float* Wr    = (const float*)d_in[5];
  const float* br    = (const float*)d_in[6];
  const float* We    = (const float*)d_in[7];
  const float* att   = (const float*)d_in[8];
  const float* bias  = (const float*)d_in[9];
  float* out = (float*)d_out;

  const int N = in_sizes[0] / 128;
  const int E = in_sizes[2];
  const int NB = (N + BNODES - 1) >> BSH;
  const int NSB = (N + SBN - 1) >> SBSH;

  char* ws = (char*)d_ws;
  size_t off = 0;
  auto alloc = [&](size_t bytes) {
    void* p = ws + off;
    off = (off + bytes + 255) & ~(size_t)255;
    return p;
  };
  int2* ebkt = (int2*)alloc((size_t)NB * CAP * 8);
  // overlay: csb dead before gemm writes xlb/xrb over it
  size_t ov_start = off;
  unsigned short* xlb = (unsigned short*)alloc((size_t)N * 128 * 2);
  unsigned short* xrb = (unsigned short*)alloc((size_t)N * 128 * 2);
  int2* csb = (int2*)(ws + ov_start);   // NSB*CCAP*8 = 14.1 MB < 25.6 MB overlay
  unsigned short* WtB = (unsigned short*)alloc(2 * 16384 * 2);
  float* ql = (float*)alloc((size_t)N * 4 * 4);
  float* qr = (float*)alloc((size_t)N * 4 * 4);
  float* qe = (float*)alloc(4 * 4);
  unsigned* fcnt = (unsigned*)alloc((size_t)NB * 4);
  unsigned* gsb  = (unsigned*)alloc((size_t)NSB * 4);

  hipMemsetAsync(gsb, 0, (size_t)NSB * 4, stream);

  k_prep<<<2, 256, 0, stream>>>(Wl, Wr, We, att, WtB, qe);

  int nblk = (E + CCHUNK - 1) / CCHUNK;
  k_coarse<<<nblk, 256, 0, stream>>>(eidx, ew_in, gsb, csb, E, NSB);

  k_fine<<<NSB, 1024, 0, stream>>>(gsb, csb, ebkt, fcnt, NB);

  k_gemm<<<(N + 63) / 64, 256, 0, stream>>>(x, WtB, att, bl, br, xlb, xrb, ql, qr, N);

  k_agg<<<NB, 256, 0, stream>>>(fcnt, ebkt, xlb, xrb, ql, qr, qe, We, att, bias, out, N);
}

// Round 10
// 165.331 us; speedup vs baseline: 1.0911x; 1.0911x over previous
//
#include <hip/hip_runtime.h>
#include <cstdint>

#define NEG 0.2f
#define BSH 4
#define BNODES 16
#define CAP 768
#define EPT 3
#define SBSH 9
#define SBN 512
#define CCAP 18000
#define CCHUNK 3328
#define CEPT 13
#define LOG2E 1.44269504088896f

typedef __attribute__((ext_vector_type(8))) short short8v;
typedef __attribute__((ext_vector_type(4))) float f32x4;

__device__ __forceinline__ unsigned short f2bf(float f) {
  unsigned u = __float_as_uint(f);
  return (unsigned short)((u + 0x7FFFu + ((u >> 16) & 1u)) >> 16);
}

// ---- prep: W[k][c] f32 -> WtB[mat][c][k] bf16 (transposed) -----------------------
__global__ __launch_bounds__(256) void k_prep(const float* __restrict__ Wl,
    const float* __restrict__ Wr, unsigned short* __restrict__ WtB) {
  int mat = blockIdx.x;
  const float* W = mat ? Wr : Wl;
  for (int i = threadIdx.x; i < 16384; i += 256) {
    int c = i >> 7, k = i & 127;
    WtB[mat * 16384 + c * 128 + k] = f2bf(W[k * 128 + c]);
  }
}

// ---- MFMA GEMM (swapped operands): blockIdx.y = mat; coalesced ushort4 epilogue ---
__global__ __launch_bounds__(256) void k_gemm(const float* __restrict__ x,
    const unsigned short* __restrict__ WtB,
    const float* __restrict__ bl, const float* __restrict__ br,
    unsigned short* __restrict__ xlb, unsigned short* __restrict__ xrb, int n) {
  __shared__ __align__(16) unsigned short xs[64][136];
  __shared__ __align__(16) unsigned short Wt[128][136];
  int tid = threadIdx.x;
  int B0 = blockIdx.x * 64;
  int mat = blockIdx.y;
  for (int i = tid; i < 64 * 32; i += 256) {
    int r = i >> 5, c4 = (i & 31) * 4;
    ushort4 o = {0, 0, 0, 0};
    if (B0 + r < n) {
      float4 v = *(const float4*)(x + (size_t)(B0 + r) * 128 + c4);
      o = make_ushort4(f2bf(v.x), f2bf(v.y), f2bf(v.z), f2bf(v.w));
    }
    *(ushort4*)&xs[r][c4] = o;
  }
  for (int i = tid; i < 128 * 32; i += 256) {
    int c = i >> 5, k4 = (i & 31) * 4;
    *(ushort4*)&Wt[c][k4] = *(const ushort4*)(WtB + (size_t)mat * 16384 + c * 128 + k4);
  }
  __syncthreads();
  int wv = tid >> 6, lane = tid & 63;
  int l15 = lane & 15, g = lane >> 4;
  int R0 = wv * 16;
  f32x4 acc[8];
  #pragma unroll
  for (int t = 0; t < 8; ++t) acc[t] = {0.f, 0.f, 0.f, 0.f};
  #pragma unroll
  for (int kc = 0; kc < 4; ++kc) {
    int k0 = kc * 32 + g * 8;
    short8v b = *(const short8v*)&xs[R0 + l15][k0];        // x row -> B (N = x-row)
    #pragma unroll
    for (int t = 0; t < 8; ++t) {
      short8v a = *(const short8v*)&Wt[t * 16 + l15][k0];  // W^T row -> A (M = channel)
      acc[t] = __builtin_amdgcn_mfma_f32_16x16x32_bf16(a, b, acc[t], 0, 0, 0);
    }
  }
  // D: col(lane&15) = x-row within 16-group, row(g*4+q) = channel within tile t
  const float* bias = mat ? br : bl;
  unsigned short* yp = mat ? xrb : xlb;
  int row = B0 + R0 + l15;
  if (row < n) {
    #pragma unroll
    for (int t = 0; t < 8; ++t) {
      int c0 = t * 16 + g * 4;
      float4 bv = *(const float4*)(bias + c0);
      ushort4 o = {f2bf(acc[t][0] + bv.x), f2bf(acc[t][1] + bv.y),
                   f2bf(acc[t][2] + bv.z), f2bf(acc[t][3] + bv.w)};
      *(ushort4*)(yp + (size_t)row * 128 + c0) = o;
    }
  }
}

// ---- phase A: coarse scatter into superbucket slabs ------------------------------
__global__ __launch_bounds__(256) void k_coarse(const int* __restrict__ eidx,
    const float* __restrict__ ew, unsigned* __restrict__ gsb,
    int2* __restrict__ csb, int E, int NSB) {
  __shared__ unsigned cnt[128];
  __shared__ unsigned base[128];
  int c0 = blockIdx.x * CCHUNK;
  int c1 = min(E, c0 + CCHUNK);
  if (c0 >= c1) return;
  for (int b = threadIdx.x; b < NSB; b += 256) cnt[b] = 0u;
  __syncthreads();
  unsigned dreg[CEPT];
  #pragma unroll
  for (int k = 0; k < CEPT; ++k) {
    int i = c0 + threadIdx.x + k * 256;
    unsigned d = 0u;
    if (i < c1) {
      d = (unsigned)eidx[E + i];
      atomicAdd(&cnt[d >> SBSH], 1u);
    }
    dreg[k] = d;
  }
  __syncthreads();
  for (int b = threadIdx.x; b < NSB; b += 256) {
    unsigned c = cnt[b];
    base[b] = c ? atomicAdd(&gsb[b], c) : 0u;
    cnt[b] = 0u;
  }
  __syncthreads();
  #pragma unroll
  for (int k = 0; k < CEPT; ++k) {
    int i = c0 + threadIdx.x + k * 256;
    if (i < c1) {
      unsigned d = dreg[k];
      unsigned b = d >> SBSH;
      unsigned slot = base[b] + atomicAdd(&cnt[b], 1u);
      if (slot < CCAP)
        csb[(size_t)b * CCAP + slot] =
            make_int2((eidx[i] << SBSH) | (int)(d & (SBN - 1)), __float_as_int(ew[i]));
    }
  }
}

// ---- phase B: split superbucket into 32 fine-bucket slabs (single pass) ----------
__global__ __launch_bounds__(1024) void k_fine(const unsigned* __restrict__ gsb,
    const int2* __restrict__ csb, int2* __restrict__ ebkt,
    unsigned* __restrict__ fcnt, int NB) {
  __shared__ unsigned cnt[32];
  int sb = blockIdx.x;
  int ne = min((int)gsb[sb], CCAP);
  const int2* src = csb + (size_t)sb * CCAP;
  if (threadIdx.x < 32) cnt[threadIdx.x] = 0u;
  __syncthreads();
  for (int i = threadIdx.x; i < ne; i += 1024) {
    int2 e = src[i];
    int fb = (e.x >> 4) & 31;
    unsigned slot = atomicAdd(&cnt[fb], 1u);
    if (slot < CAP) {
      int packed = ((e.x >> SBSH) << 4) | (e.x & 15);
      ebkt[(size_t)(sb * 32 + fb) * CAP + slot] = make_int2(packed, e.y);
    }
  }
  __syncthreads();
  if (threadIdx.x < 32) {
    int fb = sb * 32 + (int)threadIdx.x;
    if (fb < NB) fcnt[fb] = min(cnt[threadIdx.x], (unsigned)CAP);
  }
}

// ---- fused: LDS counting-sort + softmax aggregation (round-8 proven form) --------
__global__ __launch_bounds__(256) void k_agg(
    const unsigned* __restrict__ fcnt, const int2* __restrict__ ebkt,
    const unsigned short* __restrict__ xlb, const unsigned short* __restrict__ xrb,
    const float* __restrict__ We, const float* __restrict__ att,
    const float* __restrict__ bias, float* __restrict__ out, int n) {
  __shared__ int2 es[CAP];
  __shared__ unsigned rp[BNODES + 1];
  __shared__ unsigned cur[BNODES];
  __shared__ unsigned scnt[BNODES];
  int tid = threadIdx.x;
  int lane = tid & 63, wv = tid >> 6;
  int bkt = blockIdx.x;
  int ne = min((int)fcnt[bkt], CAP);
  const int2* srcp = ebkt + (size_t)bkt * CAP;
  if (tid < BNODES) scnt[tid] = 0u;
  __syncthreads();
  int2 er[EPT];
  #pragma unroll
  for (int k = 0; k < EPT; ++k) {
    int i = tid + k * 256;
    if (i < ne) {
      er[k] = srcp[i];
      atomicAdd(&scnt[er[k].x & (BNODES - 1)], 1u);
    }
  }
  __syncthreads();
  if (tid < 64) {
    unsigned s = (lane < BNODES) ? scnt[lane] : 0u;
    #pragma unroll
    for (int off = 1; off < BNODES; off <<= 1) {
      unsigned t = __shfl_up(s, off);
      if (lane >= off) s += t;
    }
    if (lane < BNODES) { rp[lane + 1] = s; cur[lane] = 0u; }
    if (lane == 0) rp[0] = 0u;
  }
  __syncthreads();
  #pragma unroll
  for (int k = 0; k < EPT; ++k) {
    int i = tid + k * 256;
    if (i < ne) {
      int dl = er[k].x & (BNODES - 1);
      unsigned slot = rp[dl] + atomicAdd(&cur[dl], 1u);
      es[slot] = make_int2(er[k].x >> BSH, er[k].y);
    }
  }
  __syncthreads();

  int g = lane >> 4;          // edge-group 0..3
  int l4 = lane & 15;         // channel-lane; head = l4>>2
  int ch0 = l4 * 8;
  float4 weA = *(const float4*)(We + ch0);
  float4 weB = *(const float4*)(We + ch0 + 4);
  float4 atA = *(const float4*)(att + ch0);
  float4 atB = *(const float4*)(att + ch0 + 4);
  atA.x *= LOG2E; atA.y *= LOG2E; atA.z *= LOG2E; atA.w *= LOG2E;
  atB.x *= LOG2E; atB.y *= LOG2E; atB.z *= LOG2E; atB.w *= LOG2E;

  for (int dl = wv; dl < BNODES; dl += 4) {
    int d = (bkt << BSH) + dl;
    if (d >= n) break;
    int s0 = (int)rp[dl], s1 = (int)rp[dl + 1];
    uint4 xrq = *(const uint4*)(xrb + ((size_t)d << 7) + ch0);
    float4 xrA, xrB;
    xrA.x = __uint_as_float(xrq.x << 16);
    xrA.y = __uint_as_float(xrq.x & 0xFFFF0000u);
    xrA.z = __uint_as_float(xrq.y << 16);
    xrA.w = __uint_as_float(xrq.y & 0xFFFF0000u);
    xrB.x = __uint_as_float(xrq.z << 16);
    xrB.y = __uint_as_float(xrq.z & 0xFFFF0000u);
    xrB.z = __uint_as_float(xrq.w << 16);
    xrB.w = __uint_as_float(xrq.w & 0xFFFF0000u);
    float den = 0.f, wmax = -INFINITY;
    float4 aA = {0, 0, 0, 0}, aB = {0, 0, 0, 0};
    int idx = s0 + g;
    bool valid = idx < s1;
    int2 ev = make_int2(0, 0);
    uint4 xq = {0, 0, 0, 0};
    if (valid) {
      ev = es[idx];
      xq = *(const uint4*)(xlb + ((size_t)ev.x << 7) + ch0);
    }
    for (int j = s0; j < s1; j += 4) {
      int idxn = j + 4 + g;
      bool vn = idxn < s1;
      int2 evn = ev; uint4 xqn = xq;
      if (vn) {
        evn = es[idxn];
        xqn = *(const uint4*)(xlb + ((size_t)evn.x << 7) + ch0);
      }
      if (valid) {
        float w = __int_as_float(ev.y);
        wmax = fmaxf(wmax, w);
        float4 xA, xB;
        xA.x = __uint_as_float(xq.x << 16);
        xA.y = __uint_as_float(xq.x & 0xFFFF0000u);
        xA.z = __uint_as_float(xq.y << 16);
        xA.w = __uint_as_float(xq.y & 0xFFFF0000u);
        xB.x = __uint_as_float(xq.z << 16);
        xB.y = __uint_as_float(xq.z & 0xFFFF0000u);
        xB.z = __uint_as_float(xq.w << 16);
        xB.w = __uint_as_float(xq.w & 0xFFFF0000u);
        float4 tA, tB;
        tA.x = xA.x + xrA.x + w * weA.x;
        tA.y = xA.y + xrA.y + w * weA.y;
        tA.z = xA.z + xrA.z + w * weA.z;
        tA.w = xA.w + xrA.w + w * weA.w;
        tB.x = xB.x + xrB.x + w * weB.x;
        tB.y = xB.y + xrB.y + w * weB.y;
        tB.z = xB.z + xrB.z + w * weB.z;
        tB.w = xB.w + xrB.w + w * weB.w;
        tA.x = fmaxf(tA.x, NEG * tA.x);
        tA.y = fmaxf(tA.y, NEG * tA.y);
        tA.z = fmaxf(tA.z, NEG * tA.z);
        tA.w = fmaxf(tA.w, NEG * tA.w);
        tB.x = fmaxf(tB.x, NEG * tB.x);
        tB.y = fmaxf(tB.y, NEG * tB.y);
        tB.z = fmaxf(tB.z, NEG * tB.z);
        tB.w = fmaxf(tB.w, NEG * tB.w);
        float p = tA.x * atA.x + tA.y * atA.y + tA.z * atA.z + tA.w * atA.w
                + tB.x * atB.x + tB.y * atB.y + tB.z * atB.z + tB.w * atB.w;
        p += __shfl_xor(p, 1);
        p += __shfl_xor(p, 2);
        float pe = exp2f(p);
        den += pe;
        aA.x += pe * xA.x; aA.y += pe * xA.y; aA.z += pe * xA.z; aA.w += pe * xA.w;
        aB.x += pe * xB.x; aB.y += pe * xB.y; aB.z += pe * xB.z; aB.w += pe * xB.w;
      }
      ev = evn; xq = xqn; valid = vn;
    }
    #pragma unroll
    for (int mask = 16; mask <= 32; mask <<= 1) {
      den += __shfl_xor(den, mask);
      aA.x += __shfl_xor(aA.x, mask); aA.y += __shfl_xor(aA.y, mask);
      aA.z += __shfl_xor(aA.z, mask); aA.w += __shfl_xor(aA.w, mask);
      aB.x += __shfl_xor(aB.x, mask); aB.y += __shfl_xor(aB.y, mask);
      aB.z += __shfl_xor(aB.z, mask); aB.w += __shfl_xor(aB.w, mask);
      wmax = fmaxf(wmax, __shfl_xor(wmax, mask));
    }
    // self-loop: weight = max incoming edge weight (0 if none)
    {
      float wl = (wmax > -INFINITY) ? wmax : 0.f;
      uint4 xq2 = *(const uint4*)(xlb + ((size_t)d << 7) + ch0);
      float4 xA, xB;
      xA.x = __uint_as_float(xq2.x << 16);
      xA.y = __uint_as_float(xq2.x & 0xFFFF0000u);
      xA.z = __uint_as_float(xq2.y << 16);
      xA.w = __uint_as_float(xq2.y & 0xFFFF0000u);
      xB.x = __uint_as_float(xq2.z << 16);
      xB.y = __uint_as_float(xq2.z & 0xFFFF0000u);
      xB.z = __uint_as_float(xq2.w << 16);
      xB.w = __uint_as_float(xq2.w & 0xFFFF0000u);
      float4 tA, tB;
      tA.x = xA.x + xrA.x + wl * weA.x;
      tA.y = xA.y + xrA.y + wl * weA.y;
      tA.z = xA.z + xrA.z + wl * weA.z;
      tA.w = xA.w + xrA.w + wl * weA.w;
      tB.x = xB.x + xrB.x + wl * weB.x;
      tB.y = xB.y + xrB.y + wl * weB.y;
      tB.z = xB.z + xrB.z + wl * weB.z;
      tB.w = xB.w + xrB.w + wl * weB.w;
      tA.x = fmaxf(tA.x, NEG * tA.x);
      tA.y = fmaxf(tA.y, NEG * tA.y);
      tA.z = fmaxf(tA.z, NEG * tA.z);
      tA.w = fmaxf(tA.w, NEG * tA.w);
      tB.x = fmaxf(tB.x, NEG * tB.x);
      tB.y = fmaxf(tB.y, NEG * tB.y);
      tB.z = fmaxf(tB.z, NEG * tB.z);
      tB.w = fmaxf(tB.w, NEG * tB.w);
      float p = tA.x * atA.x + tA.y * atA.y + tA.z * atA.z + tA.w * atA.w
              + tB.x * atB.x + tB.y * atB.y + tB.z * atB.z + tB.w * atB.w;
      p += __shfl_xor(p, 1);
      p += __shfl_xor(p, 2);
      float pe = exp2f(p);
      den += pe;
      aA.x += pe * xA.x; aA.y += pe * xA.y; aA.z += pe * xA.z; aA.w += pe * xA.w;
      aB.x += pe * xB.x; aB.y += pe * xB.y; aB.z += pe * xB.z; aB.w += pe * xB.w;
    }
    if (g == 0) {
      float r = 1.0f / den;
      float4 bvA = *(const float4*)(bias + ch0);
      float4 bvB = *(const float4*)(bias + ch0 + 4);
      float* op = out + (size_t)d * 128 + ch0;
      float4 oA = {aA.x * r + bvA.x, aA.y * r + bvA.y, aA.z * r + bvA.z, aA.w * r + bvA.w};
      float4 oB = {aB.x * r + bvB.x, aB.y * r + bvB.y, aB.z * r + bvB.z, aB.w * r + bvB.w};
      *(float4*)op = oA;
      *(float4*)(op + 4) = oB;
    }
  }
}

extern "C" void kernel_launch(void* const* d_in, const int* in_sizes, int n_in,
                              void* d_out, int out_size, void* d_ws, size_t ws_size,
                              hipStream_t stream) {
  const float* x     = (const float*)d_in[0];
  const int*   eidx  = (const int*)d_in[1];
  const float* ew_in = (const float*)d_in[2];
  const float* Wl    = (const float*)d_in[3];
  const float* bl    = (const float*)d_in[4];
  const float* Wr    = (const float*)d_in[5];
  const float* br    = (const float*)d_in[6];
  const float* We    = (const float*)d_in[7];
  const float* att   = (const float*)d_in[8];
  const float* bias  = (const float*)d_in[9];
  float* out = (float*)d_out;

  const int N = in_sizes[0] / 128;
  const int E = in_sizes[2];
  const int NB = (N + BNODES - 1) >> BSH;
  const int NSB = (N + SBN - 1) >> SBSH;

  char* ws = (char*)d_ws;
  size_t off = 0;
  auto alloc = [&](size_t bytes) {
    void* p = ws + off;
    off = (off + bytes + 255) & ~(size_t)255;
    return p;
  };
  int2* ebkt = (int2*)alloc((size_t)NB * CAP * 8);
  // overlay: csb dead before gemm writes xlb/xrb over it
  size_t ov_start = off;
  unsigned short* xlb = (unsigned short*)alloc((size_t)N * 128 * 2);
  unsigned short* xrb = (unsigned short*)alloc((size_t)N * 128 * 2);
  int2* csb = (int2*)(ws + ov_start);   // NSB*CCAP*8 = 14.1 MB < 25.6 MB overlay
  unsigned short* WtB = (unsigned short*)alloc(2 * 16384 * 2);
  unsigned* fcnt = (unsigned*)alloc((size_t)NB * 4);
  unsigned* gsb  = (unsigned*)alloc((size_t)NSB * 4);

  hipMemsetAsync(gsb, 0, (size_t)NSB * 4, stream);

  k_prep<<<2, 256, 0, stream>>>(Wl, Wr, WtB);

  int nblk = (E + CCHUNK - 1) / CCHUNK;
  k_coarse<<<nblk, 256, 0, stream>>>(eidx, ew_in, gsb, csb, E, NSB);

  k_fine<<<NSB, 1024, 0, stream>>>(gsb, csb, ebkt, fcnt, NB);

  k_gemm<<<dim3((N + 63) / 64, 2), 256, 0, stream>>>(x, WtB, bl, br, xlb, xrb, N);

  k_agg<<<NB, 256, 0, stream>>>(fcnt, ebkt, xlb, xrb, We, att, bias, out, N);
}

// Round 11
// 162.570 us; speedup vs baseline: 1.1097x; 1.0170x over previous
//
#include <hip/hip_runtime.h>
#include <cstdint>

#define NEG 0.2f
#define BSH 4
#define BNODES 16
#define CAP 768
#define EPT 3
#define SBSH 9
#define SBN 512
#define CCAP 18000
#define CCHUNK 3328
#define CEPT 13
#define FSLICE 8
#define LOG2E 1.44269504088896f

typedef __attribute__((ext_vector_type(8))) short short8v;
typedef __attribute__((ext_vector_type(4))) float f32x4;

__device__ __forceinline__ unsigned short f2bf(float f) {
  unsigned u = __float_as_uint(f);
  return (unsigned short)((u + 0x7FFFu + ((u >> 16) & 1u)) >> 16);
}
__device__ __forceinline__ float bf2f(unsigned short h) {
  return __uint_as_float(((unsigned)h) << 16);
}

// ---- prep: W[k][c] f32 -> WtB[mat][c][k] bf16; qe[h] = 0.6*log2e*(att_h . We_h) ---
__global__ __launch_bounds__(256) void k_prep(const float* __restrict__ Wl,
    const float* __restrict__ Wr, const float* __restrict__ We,
    const float* __restrict__ att, unsigned short* __restrict__ WtB,
    float* __restrict__ qe) {
  int mat = blockIdx.x;
  const float* W = mat ? Wr : Wl;
  for (int i = threadIdx.x; i < 16384; i += 256) {
    int c = i >> 7, k = i & 127;
    WtB[mat * 16384 + c * 128 + k] = f2bf(W[k * 128 + c]);
  }
  if (mat == 0) {
    __shared__ float tmp[128];
    if (threadIdx.x < 128) tmp[threadIdx.x] = att[threadIdx.x] * We[threadIdx.x];
    __syncthreads();
    if (threadIdx.x < 4) {
      float s = 0.f;
      for (int c = 0; c < 32; ++c) s += tmp[threadIdx.x * 32 + c];
      qe[threadIdx.x] = 0.6f * LOG2E * s;
    }
  }
}

// ---- MFMA GEMM (swapped operands) + ql/qr epilogue dots --------------------------
__global__ __launch_bounds__(256) void k_gemm(const float* __restrict__ x,
    const unsigned short* __restrict__ WtB, const float* __restrict__ att,
    const float* __restrict__ bl, const float* __restrict__ br,
    unsigned short* __restrict__ xlb, unsigned short* __restrict__ xrb,
    float* __restrict__ ql, float* __restrict__ qr, int n) {
  __shared__ __align__(16) unsigned short xs[64][136];
  __shared__ __align__(16) unsigned short Wt[128][136];
  int tid = threadIdx.x;
  int B0 = blockIdx.x * 64;
  int mat = blockIdx.y;
  for (int i = tid; i < 64 * 32; i += 256) {
    int r = i >> 5, c4 = (i & 31) * 4;
    ushort4 o = {0, 0, 0, 0};
    if (B0 + r < n) {
      float4 v = *(const float4*)(x + (size_t)(B0 + r) * 128 + c4);
      o = make_ushort4(f2bf(v.x), f2bf(v.y), f2bf(v.z), f2bf(v.w));
    }
    *(ushort4*)&xs[r][c4] = o;
  }
  for (int i = tid; i < 128 * 32; i += 256) {
    int c = i >> 5, k4 = (i & 31) * 4;
    *(ushort4*)&Wt[c][k4] = *(const ushort4*)(WtB + (size_t)mat * 16384 + c * 128 + k4);
  }
  __syncthreads();
  int wv = tid >> 6, lane = tid & 63;
  int l15 = lane & 15, g = lane >> 4;
  int R0 = wv * 16;
  f32x4 acc[8];
  #pragma unroll
  for (int t = 0; t < 8; ++t) acc[t] = {0.f, 0.f, 0.f, 0.f};
  #pragma unroll
  for (int kc = 0; kc < 4; ++kc) {
    int k0 = kc * 32 + g * 8;
    short8v b = *(const short8v*)&xs[R0 + l15][k0];
    #pragma unroll
    for (int t = 0; t < 8; ++t) {
      short8v a = *(const short8v*)&Wt[t * 16 + l15][k0];
      acc[t] = __builtin_amdgcn_mfma_f32_16x16x32_bf16(a, b, acc[t], 0, 0, 0);
    }
  }
  const float* bias = mat ? br : bl;
  unsigned short* yp = mat ? xrb : xlb;
  float* qdst = mat ? qr : ql;
  int row = B0 + R0 + l15;
  float qp[4] = {0.f, 0.f, 0.f, 0.f};
  if (row < n) {
    const float s06 = 0.6f * LOG2E;
    #pragma unroll
    for (int t = 0; t < 8; ++t) {
      int c0 = t * 16 + g * 4;
      float4 bv = *(const float4*)(bias + c0);
      float4 av = *(const float4*)(att + c0);
      ushort4 o = {f2bf(acc[t][0] + bv.x), f2bf(acc[t][1] + bv.y),
                   f2bf(acc[t][2] + bv.z), f2bf(acc[t][3] + bv.w)};
      *(ushort4*)(yp + (size_t)row * 128 + c0) = o;
      float dot = av.x * bf2f(o.x) + av.y * bf2f(o.y)
                + av.z * bf2f(o.z) + av.w * bf2f(o.w);
      qp[t >> 1] += s06 * dot;
    }
  }
  #pragma unroll
  for (int h = 0; h < 4; ++h) {
    qp[h] += __shfl_xor(qp[h], 16);
    qp[h] += __shfl_xor(qp[h], 32);
  }
  if (row < n && g == 0)
    *(float4*)(qdst + (size_t)row * 4) = make_float4(qp[0], qp[1], qp[2], qp[3]);
}

// ---- phase A: coarse scatter into superbucket slabs ------------------------------
__global__ __launch_bounds__(256) void k_coarse(const int* __restrict__ eidx,
    const float* __restrict__ ew, unsigned* __restrict__ gsb,
    int2* __restrict__ csb, int E, int NSB) {
  __shared__ unsigned cnt[128];
  __shared__ unsigned base[128];
  int c0 = blockIdx.x * CCHUNK;
  int c1 = min(E, c0 + CCHUNK);
  if (c0 >= c1) return;
  for (int b = threadIdx.x; b < NSB; b += 256) cnt[b] = 0u;
  __syncthreads();
  unsigned dreg[CEPT];
  #pragma unroll
  for (int k = 0; k < CEPT; ++k) {
    int i = c0 + threadIdx.x + k * 256;
    unsigned d = 0u;
    if (i < c1) {
      d = (unsigned)eidx[E + i];
      atomicAdd(&cnt[d >> SBSH], 1u);
    }
    dreg[k] = d;
  }
  __syncthreads();
  for (int b = threadIdx.x; b < NSB; b += 256) {
    unsigned c = cnt[b];
    base[b] = c ? atomicAdd(&gsb[b], c) : 0u;
    cnt[b] = 0u;
  }
  __syncthreads();
  #pragma unroll
  for (int k = 0; k < CEPT; ++k) {
    int i = c0 + threadIdx.x + k * 256;
    if (i < c1) {
      unsigned d = dreg[k];
      unsigned b = d >> SBSH;
      unsigned slot = base[b] + atomicAdd(&cnt[b], 1u);
      if (slot < CCAP)
        csb[(size_t)b * CCAP + slot] =
            make_int2((eidx[i] << SBSH) | (int)(d & (SBN - 1)), __float_as_int(ew[i]));
    }
  }
}

// ---- phase B: sliced split into 32 fine-bucket slabs (global reserve on fcnt) ----
__global__ __launch_bounds__(256) void k_fine(const unsigned* __restrict__ gsb,
    const int2* __restrict__ csb, int2* __restrict__ ebkt,
    unsigned* __restrict__ fcnt, int NB) {
  __shared__ unsigned cnt[32];
  __shared__ unsigned base[32];
  int sb = blockIdx.x / FSLICE;
  int sl = blockIdx.x % FSLICE;
  int ne = min((int)gsb[sb], CCAP);
  int chunk = (ne + FSLICE - 1) / FSLICE;
  int i0 = sl * chunk, i1 = min(ne, i0 + chunk);
  if (i0 >= i1) return;
  const int2* src = csb + (size_t)sb * CCAP;
  if (threadIdx.x < 32) cnt[threadIdx.x] = 0u;
  __syncthreads();
  for (int i = i0 + threadIdx.x; i < i1; i += 256)
    atomicAdd(&cnt[(src[i].x >> 4) & 31], 1u);
  __syncthreads();
  if (threadIdx.x < 32) {
    unsigned c = cnt[threadIdx.x];
    base[threadIdx.x] = c ? atomicAdd(&fcnt[sb * 32 + (int)threadIdx.x], c) : 0u;
    cnt[threadIdx.x] = 0u;
  }
  __syncthreads();
  for (int i = i0 + threadIdx.x; i < i1; i += 256) {
    int2 e = src[i];
    int fb = (e.x >> 4) & 31;
    unsigned slot = base[fb] + atomicAdd(&cnt[fb], 1u);
    if (slot < CAP) {
      int packed = ((e.x >> SBSH) << 4) | (e.x & 15);
      ebkt[(size_t)(sb * 32 + fb) * CAP + slot] = make_int2(packed, e.y);
    }
  }
}

// ---- fused: LDS counting-sort + softmax agg (8ch/lane, decomposed leaky-dot) -----
__global__ __launch_bounds__(256) void k_agg(
    const unsigned* __restrict__ fcnt, const int2* __restrict__ ebkt,
    const unsigned short* __restrict__ xlb, const unsigned short* __restrict__ xrb,
    const float* __restrict__ ql, const float* __restrict__ qr,
    const float* __restrict__ qe, const float* __restrict__ We,
    const float* __restrict__ att, const float* __restrict__ bias,
    float* __restrict__ out, int n) {
  __shared__ int2 es[CAP];
  __shared__ unsigned rp[BNODES + 1];
  __shared__ unsigned cur[BNODES];
  __shared__ unsigned scnt[BNODES];
  int tid = threadIdx.x;
  int lane = tid & 63, wv = tid >> 6;
  int bkt = blockIdx.x;
  int ne = min((int)fcnt[bkt], CAP);
  const int2* srcp = ebkt + (size_t)bkt * CAP;
  if (tid < BNODES) scnt[tid] = 0u;
  __syncthreads();
  int2 er[EPT];
  #pragma unroll
  for (int k = 0; k < EPT; ++k) {
    int i = tid + k * 256;
    if (i < ne) {
      er[k] = srcp[i];
      atomicAdd(&scnt[er[k].x & (BNODES - 1)], 1u);
    }
  }
  __syncthreads();
  if (tid < 64) {
    unsigned s = (lane < BNODES) ? scnt[lane] : 0u;
    #pragma unroll
    for (int off = 1; off < BNODES; off <<= 1) {
      unsigned t = __shfl_up(s, off);
      if (lane >= off) s += t;
    }
    if (lane < BNODES) { rp[lane + 1] = s; cur[lane] = 0u; }
    if (lane == 0) rp[0] = 0u;
  }
  __syncthreads();
  #pragma unroll
  for (int k = 0; k < EPT; ++k) {
    int i = tid + k * 256;
    if (i < ne) {
      int dl = er[k].x & (BNODES - 1);
      unsigned slot = rp[dl] + atomicAdd(&cur[dl], 1u);
      es[slot] = make_int2(er[k].x >> BSH, er[k].y);
    }
  }
  __syncthreads();

  int g = lane >> 4;          // edge-group 0..3
  int l4 = lane & 15;         // channel-lane
  int h = l4 >> 2;            // head
  int ch0 = l4 * 8;
  float4 weA = *(const float4*)(We + ch0);
  float4 weB = *(const float4*)(We + ch0 + 4);
  float4 atA = *(const float4*)(att + ch0);
  float4 atB = *(const float4*)(att + ch0 + 4);
  const float s04 = 0.4f * LOG2E;
  atA.x *= s04; atA.y *= s04; atA.z *= s04; atA.w *= s04;
  atB.x *= s04; atB.y *= s04; atB.z *= s04; atB.w *= s04;
  float qeh = qe[h];

  for (int dl = wv; dl < BNODES; dl += 4) {
    int d = (bkt << BSH) + dl;
    if (d >= n) break;
    int s0 = (int)rp[dl], s1 = (int)rp[dl + 1];
    uint4 xrq = *(const uint4*)(xrb + ((size_t)d << 7) + ch0);
    float4 xrA, xrB;
    xrA.x = __uint_as_float(xrq.x << 16);
    xrA.y = __uint_as_float(xrq.x & 0xFFFF0000u);
    xrA.z = __uint_as_float(xrq.y << 16);
    xrA.w = __uint_as_float(xrq.y & 0xFFFF0000u);
    xrB.x = __uint_as_float(xrq.z << 16);
    xrB.y = __uint_as_float(xrq.z & 0xFFFF0000u);
    xrB.z = __uint_as_float(xrq.w << 16);
    xrB.w = __uint_as_float(xrq.w & 0xFFFF0000u);
    float qrd = qr[(size_t)d * 4 + h];
    float den = 0.f, wmax = -INFINITY;
    float4 aA = {0, 0, 0, 0}, aB = {0, 0, 0, 0};
    int idx = s0 + g;
    bool valid = idx < s1;
    int2 ev = make_int2(0, 0);
    uint4 xq = {0, 0, 0, 0};
    float qls = 0.f;
    if (valid) {
      ev = es[idx];
      xq = *(const uint4*)(xlb + ((size_t)ev.x << 7) + ch0);
      qls = ql[(size_t)ev.x * 4 + h];
    }
    for (int j = s0; j < s1; j += 4) {
      int idxn = j + 4 + g;
      bool vn = idxn < s1;
      int2 evn = ev; uint4 xqn = xq; float qln = qls;
      if (vn) {
        evn = es[idxn];
        xqn = *(const uint4*)(xlb + ((size_t)evn.x << 7) + ch0);
        qln = ql[(size_t)evn.x * 4 + h];
      }
      if (valid) {
        float w = __int_as_float(ev.y);
        wmax = fmaxf(wmax, w);
        float4 xA, xB;
        xA.x = __uint_as_float(xq.x << 16);
        xA.y = __uint_as_float(xq.x & 0xFFFF0000u);
        xA.z = __uint_as_float(xq.y << 16);
        xA.w = __uint_as_float(xq.y & 0xFFFF0000u);
        xB.x = __uint_as_float(xq.z << 16);
        xB.y = __uint_as_float(xq.z & 0xFFFF0000u);
        xB.z = __uint_as_float(xq.w << 16);
        xB.w = __uint_as_float(xq.w & 0xFFFF0000u);
        float nl = 0.f, t;
        t = xA.x + fmaf(w, weA.x, xrA.x); nl = fmaf(atA.x, fabsf(t), nl);
        t = xA.y + fmaf(w, weA.y, xrA.y); nl = fmaf(atA.y, fabsf(t), nl);
        t = xA.z + fmaf(w, weA.z, xrA.z); nl = fmaf(atA.z, fabsf(t), nl);
        t = xA.w + fmaf(w, weA.w, xrA.w); nl = fmaf(atA.w, fabsf(t), nl);
        t = xB.x + fmaf(w, weB.x, xrB.x); nl = fmaf(atB.x, fabsf(t), nl);
        t = xB.y + fmaf(w, weB.y, xrB.y); nl = fmaf(atB.y, fabsf(t), nl);
        t = xB.z + fmaf(w, weB.z, xrB.z); nl = fmaf(atB.z, fabsf(t), nl);
        t = xB.w + fmaf(w, weB.w, xrB.w); nl = fmaf(atB.w, fabsf(t), nl);
        nl += __shfl_xor(nl, 1);
        nl += __shfl_xor(nl, 2);
        float pe = exp2f(qls + fmaf(w, qeh, qrd) + nl);
        den += pe;
        aA.x += pe * xA.x; aA.y += pe * xA.y; aA.z += pe * xA.z; aA.w += pe * xA.w;
        aB.x += pe * xB.x; aB.y += pe * xB.y; aB.z += pe * xB.z; aB.w += pe * xB.w;
      }
      ev = evn; xq = xqn; qls = qln; valid = vn;
    }
    #pragma unroll
    for (int mask = 16; mask <= 32; mask <<= 1) {
      den += __shfl_xor(den, mask);
      aA.x += __shfl_xor(aA.x, mask); aA.y += __shfl_xor(aA.y, mask);
      aA.z += __shfl_xor(aA.z, mask); aA.w += __shfl_xor(aA.w, mask);
      aB.x += __shfl_xor(aB.x, mask); aB.y += __shfl_xor(aB.y, mask);
      aB.z += __shfl_xor(aB.z, mask); aB.w += __shfl_xor(aB.w, mask);
      wmax = fmaxf(wmax, __shfl_xor(wmax, mask));
    }
    // self-loop: weight = max incoming edge weight (0 if none)
    {
      float wl = (wmax > -INFINITY) ? wmax : 0.f;
      uint4 xq2 = *(const uint4*)(xlb + ((size_t)d << 7) + ch0);
      float4 xA, xB;
      xA.x = __uint_as_float(xq2.x << 16);
      xA.y = __uint_as_float(xq2.x & 0xFFFF0000u);
      xA.z = __uint_as_float(xq2.y << 16);
      xA.w = __uint_as_float(xq2.y & 0xFFFF0000u);
      xB.x = __uint_as_float(xq2.z << 16);
      xB.y = __uint_as_float(xq2.z & 0xFFFF0000u);
      xB.z = __uint_as_float(xq2.w << 16);
      xB.w = __uint_as_float(xq2.w & 0xFFFF0000u);
      float nl = 0.f, t;
      t = xA.x + fmaf(wl, weA.x, xrA.x); nl = fmaf(atA.x, fabsf(t), nl);
      t = xA.y + fmaf(wl, weA.y, xrA.y); nl = fmaf(atA.y, fabsf(t), nl);
      t = xA.z + fmaf(wl, weA.z, xrA.z); nl = fmaf(atA.z, fabsf(t), nl);
      t = xA.w + fmaf(wl, weA.w, xrA.w); nl = fmaf(atA.w, fabsf(t), nl);
      t = xB.x + fmaf(wl, weB.x, xrB.x); nl = fmaf(atB.x, fabsf(t), nl);
      t = xB.y + fmaf(wl, weB.y, xrB.y); nl = fmaf(atB.y, fabsf(t), nl);
      t = xB.z + fmaf(wl, weB.z, xrB.z); nl = fmaf(atB.z, fabsf(t), nl);
      t = xB.w + fmaf(wl, weB.w, xrB.w); nl = fmaf(atB.w, fabsf(t), nl);
      nl += __shfl_xor(nl, 1);
      nl += __shfl_xor(nl, 2);
      float qld = ql[(size_t)d * 4 + h];
      float pe = exp2f(qld + fmaf(wl, qeh, qrd) + nl);
      den += pe;
      aA.x += pe * xA.x; aA.y += pe * xA.y; aA.z += pe * xA.z; aA.w += pe * xA.w;
      aB.x += pe * xB.x; aB.y += pe * xB.y; aB.z += pe * xB.z; aB.w += pe * xB.w;
    }
    if (g == 0) {
      float r = 1.0f / den;
      float4 bvA = *(const float4*)(bias + ch0);
      float4 bvB = *(const float4*)(bias + ch0 + 4);
      float* op = out + (size_t)d * 128 + ch0;
      float4 oA = {aA.x * r + bvA.x, aA.y * r + bvA.y, aA.z * r + bvA.z, aA.w * r + bvA.w};
      float4 oB = {aB.x * r + bvB.x, aB.y * r + bvB.y, aB.z * r + bvB.z, aB.w * r + bvB.w};
      *(float4*)op = oA;
      *(float4*)(op + 4) = oB;
    }
  }
}

extern "C" void kernel_launch(void* const* d_in, const int* in_sizes, int n_in,
                              void* d_out, int out_size, void* d_ws, size_t ws_size,
                              hipStream_t stream) {
  const float* x     = (const float*)d_in[0];
  const int*   eidx  = (const int*)d_in[1];
  const float* ew_in = (const float*)d_in[2];
  const float* Wl    = (const float*)d_in[3];
  const float* bl    = (const float*)d_in[4];
  const float* Wr    = (const float*)d_in[5];
  const float* br    = (const float*)d_in[6];
  const float* We    = (const float*)d_in[7];
  const float* att   = (const float*)d_in[8];
  const float* bias  = (const float*)d_in[9];
  float* out = (float*)d_out;

  const int N = in_sizes[0] / 128;
  const int E = in_sizes[2];
  const int NB = (N + BNODES - 1) >> BSH;
  const int NSB = (N + SBN - 1) >> SBSH;

  char* ws = (char*)d_ws;
  size_t off = 0;
  auto alloc = [&](size_t bytes) {
    void* p = ws + off;
    off = (off + bytes + 255) & ~(size_t)255;
    return p;
  };
  int2* ebkt = (int2*)alloc((size_t)NB * CAP * 8);
  // overlay: csb dead before gemm writes xlb/xrb over it
  size_t ov_start = off;
  unsigned short* xlb = (unsigned short*)alloc((size_t)N * 128 * 2);
  unsigned short* xrb = (unsigned short*)alloc((size_t)N * 128 * 2);
  int2* csb = (int2*)(ws + ov_start);   // NSB*CCAP*8 = 14.1 MB < 25.6 MB overlay
  unsigned short* WtB = (unsigned short*)alloc(2 * 16384 * 2);
  float* ql = (float*)alloc((size_t)N * 4 * 4);
  float* qr = (float*)alloc((size_t)N * 4 * 4);
  float* qe = (float*)alloc(4 * 4);
  unsigned* fcnt = (unsigned*)alloc((size_t)NB * 4);
  unsigned* gsb  = (unsigned*)alloc((size_t)NSB * 4);

  // zero fcnt..gsb in one memset (adjacent allocations)
  size_t z0 = (size_t)((char*)fcnt - ws);
  size_t z1 = (size_t)((char*)gsb - ws) + (size_t)NSB * 4;
  hipMemsetAsync(ws + z0, 0, z1 - z0, stream);

  k_prep<<<2, 256, 0, stream>>>(Wl, Wr, We, att, WtB, qe);

  int nblk = (E + CCHUNK - 1) / CCHUNK;
  k_coarse<<<nblk, 256, 0, stream>>>(eidx, ew_in, gsb, csb, E, NSB);

  k_fine<<<NSB * FSLICE, 256, 0, stream>>>(gsb, csb, ebkt, fcnt, NB);

  k_gemm<<<dim3((N + 63) / 64, 2), 256, 0, stream>>>(x, WtB, att, bl, br, xlb, xrb, ql, qr, N);

  k_agg<<<NB, 256, 0, stream>>>(fcnt, ebkt, xlb, xrb, ql, qr, qe, We, att, bias, out, N);
}